// Round 3
// baseline (321.413 us; speedup 1.0000x reference)
//
#include <hip/hip_runtime.h>

#define NJ  55
#define BLK 256

// 4-byte-aligned vector types: weight rows start at n*220 B, which is only
// dword-aligned. gfx9 global loads need only dword alignment for dwordx2/x4,
// so these still compile to single global_load_dwordx4/x2 instructions.
typedef float f4 __attribute__((ext_vector_type(4), aligned(4)));
typedef float f2 __attribute__((ext_vector_type(2), aligned(4)));

// Pure-streaming LBS, no LDS:
//  - each lane loads its OWN 55-float weight row into registers
//    (13 x dwordx4 + dwordx2 + dword, all independent -> scheduler hoists
//    several chunks, every wave keeps multiple KB in flight)
//  - every 16 B request is unique bytes (requests are disjoint row chunks),
//    so HBM traffic is identical to the staged version (232 MB fetch);
//    what changes is structure: no LDS allocation, no wave-wide drain,
//    no ds_read on the critical path
//  - occupancy: no LDS + ~96 VGPR -> 4 waves/SIMD = 16 waves/CU (vs 11
//    LDS-limited before): pure TLP latency hiding, like a memcpy kernel
//  - SE3 (3.5 KB) read at wave-uniform addresses -> scalar s_load + K$ hits,
//    zero VGPR cost, no interaction with the vector-memory pipe
__global__ __launch_bounds__(BLK, 4) void lbs_kernel(
    const float* __restrict__ points,
    const float* __restrict__ weights,
    const float* __restrict__ se3,
    float* __restrict__ out,
    int n_verts)
{
    const int n = blockIdx.x * BLK + threadIdx.x;
    if (n >= n_verts) return;

    const float* __restrict__ wrow = weights + (size_t)n * NJ;

    // ---- load the full weight row into registers (independent loads) ----
    f4 wv[13];
    #pragma unroll
    for (int i = 0; i < 13; ++i)
        wv[i] = *(const f4*)(wrow + i * 4);     // offsets 0..51
    const f2    wt2 = *(const f2*)(wrow + 52);  // 52,53
    const float wt1 = wrow[54];                 // 54

    const float px = points[n * 3 + 0];
    const float py = points[n * 3 + 1];
    const float pz = points[n * 3 + 2];

    const float4* __restrict__ M = (const float4*)se3;  // uniform -> s_load/K$

    float a[12];
    #pragma unroll
    for (int e = 0; e < 12; ++e) a[e] = 0.f;

    // A = sum_j w[j] * SE3[j]  (rows 0..2 only; row 3 unused)
    #define LBS_STEP(J, W)                                                  \
        do {                                                                \
            const float w_ = (W);                                           \
            const float4 r0 = M[(J) * 4 + 0];                               \
            const float4 r1 = M[(J) * 4 + 1];                               \
            const float4 r2 = M[(J) * 4 + 2];                               \
            a[0] += w_*r0.x; a[1] += w_*r0.y; a[2]  += w_*r0.z; a[3]  += w_*r0.w; \
            a[4] += w_*r1.x; a[5] += w_*r1.y; a[6]  += w_*r1.z; a[7]  += w_*r1.w; \
            a[8] += w_*r2.x; a[9] += w_*r2.y; a[10] += w_*r2.z; a[11] += w_*r2.w; \
        } while (0)

    #pragma unroll
    for (int i = 0; i < 13; ++i) {
        LBS_STEP(i * 4 + 0, wv[i].x);
        LBS_STEP(i * 4 + 1, wv[i].y);
        LBS_STEP(i * 4 + 2, wv[i].z);
        LBS_STEP(i * 4 + 3, wv[i].w);
    }
    LBS_STEP(52, wt2.x);
    LBS_STEP(53, wt2.y);
    LBS_STEP(54, wt1);
    #undef LBS_STEP

    out[n * 3 + 0] = a[0]*px + a[1]*py + a[2] *pz + a[3];
    out[n * 3 + 1] = a[4]*px + a[5]*py + a[6] *pz + a[7];
    out[n * 3 + 2] = a[8]*px + a[9]*py + a[10]*pz + a[11];
}

extern "C" void kernel_launch(void* const* d_in, const int* in_sizes, int n_in,
                              void* d_out, int out_size, void* d_ws, size_t ws_size,
                              hipStream_t stream)
{
    const float* points  = (const float*)d_in[0];
    const float* weights = (const float*)d_in[1];
    const float* se3     = (const float*)d_in[2];
    float* out = (float*)d_out;

    const int n_verts = in_sizes[0] / 3;              // points is (N,3) fp32
    const int grid = (n_verts + BLK - 1) / BLK;       // 1e6/256 -> 3907
    lbs_kernel<<<grid, BLK, 0, stream>>>(points, weights, se3, out, n_verts);
}